// Round 6
// baseline (103.237 us; speedup 1.0000x reference)
//
#include <hip/hip_runtime.h>
#include <stdint.h>

#define Bb 32
#define Nn 256
#define Ee 8
#define Ff 16
#define K1 32

typedef unsigned long long u64;
typedef float f32x4 __attribute__((ext_vector_type(4)));

// Kernel A: adjacency floats -> 256-bit row bitmasks. One wave per (b,r).
__global__ void bitmask_kernel(const float* __restrict__ adj, u64* __restrict__ bm) {
    int wave = (blockIdx.x << 2) + (threadIdx.x >> 6);   // (b*N + r), 4 waves/block
    int lane = threadIdx.x & 63;
    const float* row = adj + (size_t)wave * Nn;
#pragma unroll
    for (int w = 0; w < 4; ++w) {
        float v = row[w * 64 + lane];
        u64 m = __ballot(v != 0.0f);
        if (lane == 0) bm[(size_t)wave * 4 + w] = m;
    }
}

// Kernel B: per-thread BFS. 128 blocks x 64 threads (4 blocks per batch).
// Queues live in LDS (NOT per-thread arrays -> would spill to scratch).
__global__ void bfs_kernel(const u64* __restrict__ bm, uint32_t* __restrict__ proc32) {
    __shared__ u64 bml[Nn * 4];          // 8 KB: bitmask rows for this batch
    __shared__ uint8_t order[64 * K1];   // 2 KB: BFS order for this block's 64 starts
    int b = blockIdx.x >> 2;
    int g = blockIdx.x & 3;
    int t = threadIdx.x;                 // 0..63
#pragma unroll
    for (int k = 0; k < 16; ++k) bml[t + k * 64] = bm[(size_t)b * 1024 + t + k * 64];
    __syncthreads();

    int s = g * 64 + t;                  // this thread's start vertex
    u64 seen[4];
#pragma unroll
    for (int w = 0; w < 4; ++w) seen[w] = (w == (s >> 6)) ? (1ull << (s & 63)) : 0ull;
    order[t * K1] = (uint8_t)s;
    int count = 1;
    for (int i = 0; i < count && count < K1; ++i) {
        int cur = order[t * K1 + i];
#pragma unroll
        for (int w = 0; w < 4; ++w) {
            u64 nw = bml[cur * 4 + w] & ~seen[w];
            seen[w] |= nw;   // extras past 32 harmless (never dequeued)
            while (nw) {
                int bit = __builtin_ctzll(nw);
                nw &= nw - 1;
                if (count < K1) order[t * K1 + count++] = (uint8_t)(w * 64 + bit);
                else break;
            }
        }
    }
    __syncthreads();
    const uint32_t* ord32 = (const uint32_t*)order;
#pragma unroll
    for (int k = 0; k < 8; ++k)
        proc32[(size_t)b * 2048 + g * 512 + t + k * 64] = ord32[t + k * 64];
}

// Kernel C: one block per (b,s), XCD-swizzled.
// Phase 1: dependency-free streaming stores (zeros for sub_edges, sub_adj,
//          sub_feats) -- matches the pure-fill pattern (6.9 TB/s proven).
// Phase 2: compact-enumerate real edges to an LDS list.
// Phase 3: after barrier (pre-barrier stores vmcnt-drained -> ordered),
//          gather only the ~100 real 32B edge rows and overwrite.
__global__ void gather_kernel(const f32x4* __restrict__ e4,
                              const f32x4* __restrict__ feats4,
                              const u64* __restrict__ bm,
                              const uint32_t* __restrict__ proc32,
                              float* __restrict__ out) {
    int bid = blockIdx.x;
    int bs = ((bid & 7) << 10) | (bid >> 3);   // bijective: 8192 % 8 == 0
    int b = bs >> 8;
    int t = threadIdx.x;
    __shared__ int p[K1];
    __shared__ u64 bmrow[K1][4];
    __shared__ uint16_t list[1024];
    __shared__ int cnt;

    // ---- phase 1a: zero-fill sub_edges region (no dependencies at all) ----
    f32x4* out1 = (f32x4*)(out + 8388608ull) + (size_t)bs * 2048;
    f32x4 z = (f32x4){0.f, 0.f, 0.f, 0.f};
#pragma unroll
    for (int k = 0; k < 8; ++k)
        out1[t + k * 256] = z;

    if (t == 0) cnt = 0;
    if (t < 8) {
        uint32_t w = proc32[(size_t)bs * 8 + t];
        p[t * 4 + 0] = w & 255;
        p[t * 4 + 1] = (w >> 8) & 255;
        p[t * 4 + 2] = (w >> 16) & 255;
        p[t * 4 + 3] = (w >> 24) & 255;
    }
    __syncthreads();
    if (t < 128) {
        int i = t >> 2, w = t & 3;
        bmrow[i][w] = bm[((size_t)b * 256 + p[i]) * 4 + w];
    }
    __syncthreads();

    // ---- phase 1b: sub_adj (bit lookups, LDS-only deps) ----
    f32x4* out0 = (f32x4*)(out) + (size_t)bs * 256;
    {
        int i = t >> 3;
        int j0 = (t & 7) * 4;
        f32x4 a;
        int pj;
        pj = p[j0 + 0]; a.x = (float)((bmrow[i][pj >> 6] >> (pj & 63)) & 1ull);
        pj = p[j0 + 1]; a.y = (float)((bmrow[i][pj >> 6] >> (pj & 63)) & 1ull);
        pj = p[j0 + 2]; a.z = (float)((bmrow[i][pj >> 6] >> (pj & 63)) & 1ull);
        pj = p[j0 + 3]; a.w = (float)((bmrow[i][pj >> 6] >> (pj & 63)) & 1ull);
        out0[t] = a;
    }

    // ---- phase 1c: sub_feats ----
    f32x4* out2 = (f32x4*)(out + 75497472ull) + (size_t)bs * 128;
    if (t < 128) {
        int i = t >> 2, f4 = t & 3;
        out2[t] = feats4[((size_t)b * 256 + p[i]) * 4 + f4];
    }

    // ---- phase 2: compact enumeration of set (i,j) pairs ----
    int myc = 0;
#pragma unroll
    for (int q = 0; q < 4; ++q) {
        int v = t * 4 + q;
        int i = v >> 5, j = v & 31;
        int pj = p[j];
        myc += (int)((bmrow[i][pj >> 6] >> (pj & 63)) & 1ull);
    }
    int base = atomicAdd(&cnt, myc);
#pragma unroll
    for (int q = 0; q < 4; ++q) {
        int v = t * 4 + q;
        int i = v >> 5, j = v & 31;
        int pj = p[j];
        if ((bmrow[i][pj >> 6] >> (pj & 63)) & 1ull)
            list[base++] = (uint16_t)v;
    }
    __syncthreads();   // zeros drained (vmcnt 0) + list complete

    // ---- phase 3: gather & overwrite only real edges (~100 x 32B) ----
    int n2 = cnt * 2;
    for (int sidx = t; sidx < n2; sidx += 256) {
        int e = sidx >> 1, h = sidx & 1;
        int v = list[e];
        int i = v >> 5, j = v & 31;
        int pi = p[i], pj = p[j];
        out1[v * 2 + h] = e4[(((size_t)b * 256 + pi) * 256 + pj) * 2 + h];
    }
}

extern "C" void kernel_launch(void* const* d_in, const int* in_sizes, int n_in,
                              void* d_out, int out_size, void* d_ws, size_t ws_size,
                              hipStream_t stream) {
    const float* adj   = (const float*)d_in[0];
    const float* edges = (const float*)d_in[1];
    const float* feats = (const float*)d_in[2];
    float* out = (float*)d_out;

    u64* bm = (u64*)d_ws;                                          // 262144 B
    uint32_t* proc32 = (uint32_t*)((char*)d_ws + (size_t)Bb * Nn * 4 * sizeof(u64));

    bitmask_kernel<<<Bb * Nn / 4, 256, 0, stream>>>(adj, bm);
    bfs_kernel<<<Bb * 4, 64, 0, stream>>>(bm, proc32);
    gather_kernel<<<Bb * Nn, 256, 0, stream>>>((const f32x4*)edges, (const f32x4*)feats,
                                               bm, proc32, out);
}